// Round 1
// 102.261 us; speedup vs baseline: 1.0575x; 1.0575x over previous
//
#include <hip/hip_runtime.h>
#include <math.h>

// StructureLoss — R8: persistent 64-row bands + rolling 3-slot raw-t LDS window.
// R7 post-mortem: in-flight depth was NOT the limiter (Little's law needs only
// ~9KB/CU in flight; we had ~64KB). Real issue: t requested 3.9x (46-row halo
// per 16-row group + stage-2 reload) with 8MB/XCD concurrent working set vs
// 4MB L2 -> ~118MB HBM at 45-60% eff. R8: 256 blocks x 512 thr, each marches a
// 64-row band in 4x16-row steps; raw t rows live in a rolling 3x16-row LDS
// window (skewed layout), so t is fetched 1.47x and stage-2 reads t from LDS.
// Next t-block + x-tile issued as reg loads during prior iter's elementwise
// phase (issue-early/ds_write-late). Vertical running sum persists in regs.

#define IMG_H 512
#define IMG_W 512
#define NB    32
#define BANDS 8               // 64-row bands per image
#define NBLK  (NB * BANDS)    // 256 blocks, 1 per CU
#define NTH   512
#define TSR   580             // t-window row stride (floats): 512 + 64 skew + pad
#define SLOT  (16 * TSR)      // one 16-row slot
#define VST   584             // vls row stride (floats)

// skew: col c stored at c + 4*(c>>5); 32-col chunk s occupies [36s, 36s+31]
__device__ __forceinline__ float wave_reduce(float v) {
#pragma unroll
  for (int off = 32; off > 0; off >>= 1) v += __shfl_down(v, off, 64);
  return v;
}

// load one 16-row t block (rows 16b..16b+15) into 4 float4 regs, zero-fill OOR
__device__ __forceinline__ void load_blk(const float* __restrict__ tb, int b,
                                         int tid, float4* g) {
#pragma unroll
  for (int q = 0; q < 4; ++q) {
    int idx = q * NTH + tid;
    int gr  = b * 16 + (idx >> 7);
    int c4  = idx & 127;
    g[q] = ((unsigned)gr < IMG_H)
               ? *(const float4*)(tb + (size_t)gr * IMG_W + 4 * c4)
               : make_float4(0.f, 0.f, 0.f, 0.f);
  }
}

// write a staged 16-row block into LDS slot with the vidx skew
__device__ __forceinline__ void store_blk(float* dst, int slot, int tid,
                                          const float4* g) {
#pragma unroll
  for (int q = 0; q < 4; ++q) {
    int idx = q * NTH + tid;
    int r16 = idx >> 7;
    int cc  = (idx & 127) * 4;
    *(float4*)&dst[slot * SLOT + r16 * TSR + cc + 4 * (cc >> 5)] = g[q];
  }
}

// x tile for 16 rows starting at R0: thread (row=tid>>5, sub=tid&31), 16 cols
__device__ __forceinline__ void load_x(const float* __restrict__ xb, int R0,
                                       int tid, float4* g) {
  const int row = tid >> 5, sub = tid & 31;
  const float* xr = xb + (size_t)(R0 + row) * IMG_W + 16 * sub;
#pragma unroll
  for (int e = 0; e < 4; ++e) g[e] = *(const float4*)(xr + 4 * e);
}

#define ITER(K, XG, TPF, XGN, TPFN)                                            \
  {                                                                            \
    const int bbk   = bb0 + (K);                                               \
    const int R0    = bbk * 16;                                                \
    const int sPrev = (bbk + 2) % 3;                                           \
    const int sCur  = bbk % 3;                                                 \
    const int sNext = (bbk + 1) % 3;                                           \
    _Pragma("unroll")                                                          \
    for (int i = 0; i < 16; ++i) {                                             \
      const int sHd = (i >= 1) ? sNext : sCur;                                 \
      const int sTl = (i < 15) ? sPrev : sCur;                                 \
      float hd = ts[sHd * SLOT + ((i + 15) & 15) * TSR + li];                  \
      float tl = ts[sTl * SLOT + ((i + 1) & 15) * TSR + li];                   \
      sx += hd;                                                                \
      vls[i * VST + li] = sx;                                                  \
      sx -= tl;                                                                \
    }                                                                          \
    __syncthreads();                                                           \
    if ((K) < 3) {                                                             \
      store_blk(ts, sPrev, tid, TPF);                                          \
      load_x(xb, R0 + 16, tid, XGN);                                           \
    }                                                                          \
    if ((K) < 2) load_blk(tb, bbk + 3, tid, TPFN);                             \
    {                                                                          \
      const int cb = 36 * (sub >> 1) + 16 * (sub & 1);                         \
      const float* vb = &vls[s2row * VST + cb];                                \
      float q16[16];                                                           \
      float run = 0.f;                                                         \
      _Pragma("unroll")                                                        \
      for (int e = 0; e < 4; ++e) {                                            \
        float4 vv = *(const float4*)(vb + 4 * e);                              \
        q16[4 * e + 0] = run + vv.x;                                           \
        q16[4 * e + 1] = q16[4 * e + 0] + vv.y;                                \
        q16[4 * e + 2] = q16[4 * e + 1] + vv.z;                                \
        q16[4 * e + 3] = q16[4 * e + 2] + vv.w;                                \
        run = q16[4 * e + 3];                                                  \
      }                                                                        \
      float tot = q16[15], ss = tot;                                           \
      _Pragma("unroll")                                                        \
      for (int d = 1; d < 32; d <<= 1) {                                       \
        float uu = __shfl_up(ss, d, 64);                                       \
        if (sub >= d) ss += uu;                                                \
      }                                                                        \
      float pb = ss - tot;                                                     \
      _Pragma("unroll")                                                        \
      for (int j = 0; j < 16; ++j) q16[j] += pb;                               \
      float4 tq[4];                                                            \
      const float* tb2 = &ts[sCur * SLOT + s2row * TSR + cb];                  \
      _Pragma("unroll")                                                        \
      for (int e = 0; e < 4; ++e) tq[e] = *(const float4*)(tb2 + 4 * e);       \
      _Pragma("unroll")                                                        \
      for (int e = 0; e < 4; ++e) {                                            \
        float xa[4] = {XG[e].x, XG[e].y, XG[e].z, XG[e].w};                    \
        float ta[4] = {tq[e].x, tq[e].y, tq[e].z, tq[e].w};                    \
        _Pragma("unroll")                                                      \
        for (int l = 0; l < 4; ++l) {                                          \
          const int j = 4 * e + l;                                             \
          float hi;                                                            \
          if (j == 0) {                                                        \
            hi = q16[15];                                                      \
          } else {                                                             \
            float gd = __shfl_down(q16[j - 1], 1, 64);                         \
            hi = (sub == 31) ? q16[15] : gd;                                   \
          }                                                                    \
          float gu = __shfl_up(q16[j], 1, 64);                                 \
          float lo = (sub == 0) ? 0.f : gu;                                    \
          float box = hi - lo;                                                 \
          float tv = ta[l], xv = xa[l];                                        \
          float w  = fmaf(5.0f, fabsf(box * inv_area - tv), 1.0f);             \
          float ez = __expf(-fabsf(xv));                                       \
          float iv = 1.0f / (1.0f + ez);                                       \
          float p  = (xv >= 0.f) ? iv : ez * iv;                               \
          float bce = fmaxf(xv, 0.f) - xv * tv + __logf(1.0f + ez);            \
          aW += w;                                                             \
          aWB = fmaf(w, bce, aWB);                                             \
          aI  = fmaf(p * tv, w, aI);                                           \
          aU  = fmaf(p + tv, w, aU);                                           \
        }                                                                      \
      }                                                                        \
    }                                                                          \
    __syncthreads();                                                           \
  }

__global__ __launch_bounds__(NTH, 2) void sloss_main(const float* __restrict__ x,
                                                     const float* __restrict__ t,
                                                     float* __restrict__ part) {
  __shared__ __align__(16) float ts[3 * SLOT];    // 111,360 B rolling t window
  __shared__ __align__(16) float vls[16 * VST];   //  37,376 B vertical sums
  __shared__ float red[8][4];

  const int tid  = threadIdx.x;
  // band-to-XCD swizzle: all 8 bands of an image stay on one XCD's L2 so the
  // 15-row band-boundary halos get cross-block L2 hits.
  const int xcd  = blockIdx.x & 7;
  const int kb   = blockIdx.x >> 3;        // 0..31
  const int img  = (xcd << 2) | (kb >> 3); // 4 images per XCD
  const int band = kb & 7;
  const int bb0  = band * 4;               // first 16-row block of this band
  const float* tb = t + (size_t)img * (IMG_H * IMG_W);
  const float* xb = x + (size_t)img * (IMG_H * IMG_W);

  const int li    = tid + 4 * (tid >> 5);  // vidx(col) for this thread's column
  const int s2row = tid >> 5;              // stage-2 row 0..15
  const int sub   = tid & 31;              // stage-2 16-col chunk 0..31
  const float inv_area = 1.0f / 961.0f;

  // ---- prologue: stage blocks bb0-1, bb0, bb0+1 into the rolling window ----
  {
    float4 g0[4], g1[4], g2[4];
    load_blk(tb, bb0 - 1, tid, g0);
    load_blk(tb, bb0,     tid, g1);
    load_blk(tb, bb0 + 1, tid, g2);
    store_blk(ts, (bb0 + 2) % 3, tid, g0);
    store_blk(ts, (bb0 + 3) % 3, tid, g1);
    store_blk(ts, (bb0 + 4) % 3, tid, g2);
  }
  __syncthreads();

  // issue iter-0 x tile + block bb0+2 prefetch; they fly during warm-up+march
  float4 xgA[4], xgB[4], tpA[4], tpB[4];
  load_x(xb, bb0 * 16, tid, xgA);
  load_blk(tb, bb0 + 2, tid, tpA);

  // ---- warm-up: sx = sum of t rows [band*64-15, band*64+14] for col tid ----
  float sx = 0.f;
#pragma unroll
  for (int j = -15; j < 15; ++j) {
    int a = bb0 * 16 + j;                  // may be negative: >>4 floors, &15 mods
    int b = a >> 4;
    sx += ts[((b + 3) % 3) * SLOT + (a & 15) * TSR + li];
  }

  float aW = 0.f, aWB = 0.f, aI = 0.f, aU = 0.f;

  ITER(0, xgA, tpA, xgB, tpB)
  ITER(1, xgB, tpB, xgA, tpA)
  ITER(2, xgA, tpA, xgB, tpB)
  ITER(3, xgB, tpB, xgA, tpA)

  aW  = wave_reduce(aW);
  aWB = wave_reduce(aWB);
  aI  = wave_reduce(aI);
  aU  = wave_reduce(aU);
  const int wv = tid >> 6, ln = tid & 63;
  if (ln == 0) { red[wv][0] = aW; red[wv][1] = aWB; red[wv][2] = aI; red[wv][3] = aU; }
  __syncthreads();
  if (tid < 4) {
    float v = 0.f;
#pragma unroll
    for (int w8 = 0; w8 < 8; ++w8) v += red[w8][tid];
    part[(img * BANDS + band) * 4 + tid] = v;
  }
}

// ---- finalize: reduce 256 block-partials -> scalar loss ----
__global__ void sloss_final(const float* __restrict__ part,
                            float* __restrict__ out) {
  __shared__ float s[128];
  int tid = threadIdx.x;          // 128 threads
  int img = tid >> 2, q = tid & 3;
  float v = 0.f;
#pragma unroll
  for (int g = 0; g < BANDS; ++g) v += part[((img << 3) + g) * 4 + q];
  s[tid] = v;
  __syncthreads();
  float loss = 0.f;
  if (tid < NB) {
    float aW  = s[tid * 4 + 0];
    float aWB = s[tid * 4 + 1];
    float aI  = s[tid * 4 + 2];
    float aU  = s[tid * 4 + 3];
    loss = aWB / aW + 1.0f - (aI + 1.0f) / (aU - aI + 1.0f);
  }
  loss = wave_reduce(loss);
  if (tid == 0) out[0] = loss * (1.0f / (float)NB);
}

extern "C" void kernel_launch(void* const* d_in, const int* in_sizes, int n_in,
                              void* d_out, int out_size, void* d_ws, size_t ws_size,
                              hipStream_t stream) {
  const float* x = (const float*)d_in[0];
  const float* t = (const float*)d_in[1];
  float* part = (float*)d_ws;     // 256 x 4 floats, fully overwritten

  sloss_main<<<NBLK, NTH, 0, stream>>>(x, t, part);
  sloss_final<<<1, 128, 0, stream>>>(part, (float*)d_out);
}